// Round 3
// baseline (63.338 us; speedup 1.0000x reference)
//
#include <hip/hip_runtime.h>
#include <hip/hip_bf16.h>
#include <stdint.h>

#define B_ 8
#define N_ 2048
#define F_ 128
#define D_ 128

typedef short bf16x8 __attribute__((ext_vector_type(8)));
typedef float f32x4 __attribute__((ext_vector_type(4)));

__device__ __forceinline__ unsigned short f2bf(float f) {
    unsigned u = __float_as_uint(f);
    u += 0x7fffu + ((u >> 16) & 1u);
    return (unsigned short)(u >> 16);
}

// ---------------- Kernel 1: deg (blocks 0..4095) + feat (blocks 4096..4351) ----------------
// deg: one wave per adj row -> rs.  feat: gt[b][d][m] = (X@W + bias)^T bf16 (NO rs scaling).
__global__ __launch_bounds__(256) void k_degfeat(const float* __restrict__ adj,
                                                 const float* __restrict__ x,
                                                 const float* __restrict__ W,
                                                 const float* __restrict__ bias,
                                                 float* __restrict__ rs,
                                                 unsigned short* __restrict__ gt) {
    __shared__ __align__(16) unsigned char sX[64 * 128 * 2];   // feat only
    __shared__ __align__(16) unsigned char sW[128 * 128 * 2];  // feat only: W^T [d][f] bf16 swz

    const int t = threadIdx.x;
    if (blockIdx.x < 4096) {
        // ---- degree path ----
        const int wave = t >> 6, lane = t & 63;
        const int row = blockIdx.x * 4 + wave;
        const float4* p = (const float4*)(adj + (size_t)row * N_);
        float s = 0.f;
#pragma unroll
        for (int j = 0; j < 8; ++j) {
            float4 v = p[j * 64 + lane];
            s += (v.x + v.y) + (v.z + v.w);
        }
#pragma unroll
        for (int m = 1; m < 64; m <<= 1) s += __shfl_xor(s, m, 64);
        if (lane == 0) rs[row] = (s > 0.f) ? (1.0f / sqrtf(s)) : 0.f;
        return;
    }

    // ---- feat path ----
    const int R0 = (blockIdx.x - 4096) * 64;

    // build sW = W^T [d][f] bf16, swizzled: read W[f][d] coalesced, scatter b16 writes
#pragma unroll
    for (int i = 0; i < 16; ++i) {
        int c = i * 256 + t;              // 4096 chunks
        int f = c >> 5, d0 = (c & 31) * 4;
        float4 v = *(const float4*)(W + (size_t)f * D_ + d0);
        float vv[4] = {v.x, v.y, v.z, v.w};
#pragma unroll
        for (int e = 0; e < 4; ++e) {
            int dd = d0 + e;
            unsigned byte = (unsigned)(dd * 256 + f * 2);
            byte ^= ((byte >> 8) & 15u) << 4;
            *(unsigned short*)(sW + byte) = f2bf(vv[e]);
        }
    }
    // stage X rows R0..R0+63 -> sX bf16 swz
#pragma unroll
    for (int j = 0; j < 4; ++j) {
        int c = j * 256 + t;
        int row = c >> 4, sub = c & 15;
        const float4* src = (const float4*)(x + (size_t)(R0 + row) * F_ + sub * 8);
        float4 v0 = src[0], v1 = src[1];
        union { bf16x8 v; unsigned short u[8]; } pk;
        pk.u[0] = f2bf(v0.x); pk.u[1] = f2bf(v0.y); pk.u[2] = f2bf(v0.z); pk.u[3] = f2bf(v0.w);
        pk.u[4] = f2bf(v1.x); pk.u[5] = f2bf(v1.y); pk.u[6] = f2bf(v1.z); pk.u[7] = f2bf(v1.w);
        unsigned byte = (unsigned)(row * 256 + sub * 16);
        byte ^= ((byte >> 8) & 7u) << 4;
        *(bf16x8*)(sX + byte) = pk.v;
    }
    __syncthreads();

    const int w = t >> 6, l = t & 63, lr = l & 15, lh = l >> 4;
    f32x4 acc[8];
#pragma unroll
    for (int j = 0; j < 8; ++j) acc[j] = (f32x4){0.f, 0.f, 0.f, 0.f};

#pragma unroll
    for (int ks = 0; ks < 4; ++ks) {
        unsigned abyte = (unsigned)((w * 16 + lr) * 256 + lh * 16 + ks * 64);
        abyte ^= ((abyte >> 8) & 7u) << 4;
        bf16x8 a = *(const bf16x8*)(sX + abyte);
#pragma unroll
        for (int j = 0; j < 8; ++j) {
            unsigned bbyte = (unsigned)((j * 16 + lr) * 256 + lh * 16 + ks * 64);
            bbyte ^= ((bbyte >> 8) & 15u) << 4;
            bf16x8 bb = *(const bf16x8*)(sW + bbyte);
            acc[j] = __builtin_amdgcn_mfma_f32_16x16x32_bf16(a, bb, acc[j], 0, 0, 0);
        }
    }

#pragma unroll
    for (int j = 0; j < 8; ++j) {
        int d = j * 16 + lr;
        float bv = bias[d];
#pragma unroll
        for (int r = 0; r < 4; ++r) {
            int m = R0 + w * 16 + lh * 4 + r;
            int b = m >> 11, n = m & (N_ - 1);
            gt[((size_t)b * D_ + d) * N_ + n] = f2bf(acc[j][r] + bv);
        }
    }
}

// ---------------- Kernel 2: out = relu(rs[n] * (adj*rs[m]) @ gt^T) ----------------
// 256 blocks (1/CU), 512 thr (8 waves, 2r x 4c, wave tile 32x32), BM=64 BN=128 BK=128.
// Pure-DMA staging (A fp32, B bf16), counted vmcnt(8) 2-barrier pipeline, dbuf.
__global__ __launch_bounds__(512, 1) void k_gcn(const float* __restrict__ adj,
                                                const unsigned short* __restrict__ gt,
                                                const float* __restrict__ rs,
                                                float* __restrict__ out) {
    __shared__ __align__(16) unsigned char sA[2][64 * 128 * 4];   // adj tile fp32, 512B rows, swz
    __shared__ __align__(16) unsigned char sB[2][128 * 128 * 2];  // gt tile [d][k] bf16, 256B rows, swz
    __shared__ __align__(16) unsigned char sRS[N_ * 4];           // rs[b][0..2047] fp32, linear

    // XCD swizzle: 256 blocks, batch = XCD
    unsigned bid = blockIdx.x;
    unsigned wg = (bid & 7u) * 32u + (bid >> 3);
    const int b = (int)(wg >> 5);
    const int R0 = (int)(wg & 31u) * 64;

    const float* adjB = adj + (size_t)b * N_ * N_ + (size_t)R0 * N_;
    const unsigned short* gtB = gt + (size_t)b * D_ * N_;
    const float* rsB = rs + (size_t)b * N_;

    const int t = threadIdx.x;
    const int w = t >> 6, l = t & 63, lr = l & 15, lh = l >> 4;
    const int wr = w >> 2, wc = w & 3;   // wave tile: rows wr*32+..32, cols wc*32+..32

    // ---- stage: exactly 8 global_load_lds per thread ----
    auto stage = [&](int buf, int it) {
        const int k0 = it * 128;
        unsigned char* pA = sA[buf];
        unsigned char* pB = sB[buf];
#pragma unroll
        for (int i = 0; i < 4; ++i) {          // A: 2048 x 16B
            unsigned L = (unsigned)(i * 512 + t) * 16u;
            unsigned row = L >> 9, wi = L & 511u;
            unsigned wis = wi ^ ((row & 15u) << 4);
            const unsigned char* g = (const unsigned char*)adjB + (size_t)row * 8192 + (size_t)k0 * 4 + wis;
            __builtin_amdgcn_global_load_lds(
                (const __attribute__((address_space(1))) void*)g,
                (__attribute__((address_space(3))) void*)(pA + L), 16, 0, 0);
        }
#pragma unroll
        for (int i = 0; i < 4; ++i) {          // B: 2048 x 16B
            unsigned L = (unsigned)(i * 512 + t) * 16u;
            unsigned d = L >> 8, wi = L & 255u;
            unsigned wis = wi ^ ((d & 15u) << 4);
            const unsigned char* g = (const unsigned char*)gtB + (size_t)d * 4096 + (size_t)k0 * 2 + wis;
            __builtin_amdgcn_global_load_lds(
                (const __attribute__((address_space(1))) void*)g,
                (__attribute__((address_space(3))) void*)(pB + L), 16, 0, 0);
        }
    };

    // prologue: rs slab (1 chunk/thread) + stage(0) + stage(1) -> 17 in flight
    {
        unsigned L = (unsigned)t * 16u;
        __builtin_amdgcn_global_load_lds(
            (const __attribute__((address_space(1))) void*)((const unsigned char*)rsB + L),
            (__attribute__((address_space(3))) void*)(sRS + L), 16, 0, 0);
    }
    stage(0, 0);
    stage(1, 1);

    f32x4 acc[2][2];
#pragma unroll
    for (int i = 0; i < 2; ++i)
#pragma unroll
        for (int jn = 0; jn < 2; ++jn) acc[i][jn] = (f32x4){0.f, 0.f, 0.f, 0.f};

    const int NITER = N_ / 128;  // 16
#pragma unroll
    for (int it = 0; it < NITER; ++it) {
        // wait for buf[it&1]'s loads; keep next stage's 8 in flight
        if (it == NITER - 1) {
            asm volatile("s_waitcnt vmcnt(0)" ::: "memory");
        } else {
            asm volatile("s_waitcnt vmcnt(8)" ::: "memory");
        }
        __builtin_amdgcn_s_barrier();
        asm volatile("" ::: "memory");
        __builtin_amdgcn_sched_barrier(0);

        const unsigned char* pA = sA[it & 1];
        const unsigned char* pB = sB[it & 1];
#pragma unroll
        for (int kk = 0; kk < 4; ++kk) {
            // rs broadcast for this K-slice (lane-group-uniform)
            f32x4 r0 = *(const f32x4*)(sRS + it * 512 + kk * 128 + lh * 32);
            f32x4 r1 = *(const f32x4*)(sRS + it * 512 + kk * 128 + lh * 32 + 16);
            bf16x8 av[2];
#pragma unroll
            for (int i = 0; i < 2; ++i) {
                unsigned row = (unsigned)(wr * 32 + i * 16 + lr);
                unsigned base = row * 512 + (unsigned)(kk * 128 + lh * 32);
                unsigned swz = (row & 15u) << 4;
                f32x4 x0 = *(const f32x4*)(pA + (base ^ swz));
                f32x4 x1 = *(const f32x4*)(pA + ((base + 16) ^ swz));
                x0 *= r0; x1 *= r1;
                unsigned u0, u1, u2, u3;
                asm("v_cvt_pk_bf16_f32 %0, %1, %2" : "=v"(u0) : "v"(x0[0]), "v"(x0[1]));
                asm("v_cvt_pk_bf16_f32 %0, %1, %2" : "=v"(u1) : "v"(x0[2]), "v"(x0[3]));
                asm("v_cvt_pk_bf16_f32 %0, %1, %2" : "=v"(u2) : "v"(x1[0]), "v"(x1[1]));
                asm("v_cvt_pk_bf16_f32 %0, %1, %2" : "=v"(u3) : "v"(x1[2]), "v"(x1[3]));
                union { unsigned u[4]; bf16x8 v; } pk;
                pk.u[0] = u0; pk.u[1] = u1; pk.u[2] = u2; pk.u[3] = u3;
                av[i] = pk.v;
            }
            bf16x8 bv[2];
#pragma unroll
            for (int jn = 0; jn < 2; ++jn) {
                unsigned d = (unsigned)(wc * 32 + jn * 16 + lr);
                unsigned byte = d * 256 + (unsigned)(kk * 64 + lh * 16);
                byte ^= (d & 15u) << 4;
                bv[jn] = *(const bf16x8*)(pB + byte);
            }
#pragma unroll
            for (int i = 0; i < 2; ++i)
#pragma unroll
                for (int jn = 0; jn < 2; ++jn)
                    acc[i][jn] = __builtin_amdgcn_mfma_f32_16x16x32_bf16(av[i], bv[jn], acc[i][jn], 0, 0, 0);
        }

        asm volatile("s_waitcnt lgkmcnt(0)" ::: "memory");
        __builtin_amdgcn_sched_barrier(0);
        __builtin_amdgcn_s_barrier();
        if (it < NITER - 2) stage(it & 1, it + 2);
    }

    // epilogue: rs[n] * acc, relu, store fp32
#pragma unroll
    for (int i = 0; i < 2; ++i) {
#pragma unroll
        for (int reg = 0; reg < 4; ++reg) {
            int rowl = wr * 32 + i * 16 + lh * 4 + reg;
            float rsn = ((const float*)sRS)[R0 + rowl];
#pragma unroll
            for (int jn = 0; jn < 2; ++jn) {
                int d = wc * 32 + jn * 16 + lr;
                float v = acc[i][jn][reg] * rsn;
                out[((size_t)(b * N_ + R0 + rowl)) * D_ + d] = fmaxf(v, 0.f);
            }
        }
    }
}

extern "C" void kernel_launch(void* const* d_in, const int* in_sizes, int n_in,
                              void* d_out, int out_size, void* d_ws, size_t ws_size,
                              hipStream_t stream) {
    const float* inputs = (const float*)d_in[0];   // [B,N,F]
    const float* adj    = (const float*)d_in[1];   // [B,N,N]
    const float* Wk     = (const float*)d_in[2];   // [F,D]
    const float* Wb     = (const float*)d_in[3];   // [D]
    float* out = (float*)d_out;

    float* rs = (float*)d_ws;                                    // 64 KB
    unsigned short* gt = (unsigned short*)((char*)d_ws + 65536); // 4 MB

    k_degfeat<<<4096 + 256, 256, 0, stream>>>(adj, inputs, Wk, Wb, rs, gt);
    k_gcn    <<<256, 512, 0, stream>>>(adj, gt, rs, out);
}

// Round 4
// 55.642 us; speedup vs baseline: 1.1383x; 1.1383x over previous
//
#include <hip/hip_runtime.h>
#include <hip/hip_bf16.h>
#include <stdint.h>

#define B_ 8
#define N_ 2048
#define F_ 128
#define D_ 128

typedef short bf16x8 __attribute__((ext_vector_type(8)));
typedef float f32x4 __attribute__((ext_vector_type(4)));

__device__ __forceinline__ unsigned short f2bf(float f) {
    unsigned u = __float_as_uint(f);
    u += 0x7fffu + ((u >> 16) & 1u);
    return (unsigned short)(u >> 16);
}

// ---------------- Kernel 1: degrees -> rsqrt  (+ W transpose in tail blocks) ----------------
__global__ __launch_bounds__(256) void k_degwt(const float* __restrict__ adj,
                                               const float* __restrict__ W,
                                               float* __restrict__ rs,
                                               unsigned short* __restrict__ Wt) {
    if (blockIdx.x < 4096) {
        const int wave = threadIdx.x >> 6, lane = threadIdx.x & 63;
        const int row = blockIdx.x * 4 + wave;          // 0..B_*N_-1
        const float4* p = (const float4*)(adj + (size_t)row * N_);
        float s = 0.f;
#pragma unroll
        for (int j = 0; j < 8; ++j) {
            float4 v = p[j * 64 + lane];
            s += (v.x + v.y) + (v.z + v.w);
        }
#pragma unroll
        for (int m = 1; m < 64; m <<= 1) s += __shfl_xor(s, m, 64);
        if (lane == 0) rs[row] = (s > 0.f) ? (1.0f / sqrtf(s)) : 0.f;
    } else {
        int c = (blockIdx.x - 4096) * 256 + threadIdx.x;
        int d = c >> 4, f0 = (c & 15) * 8;
        union { bf16x8 v; unsigned short u[8]; } pk;
#pragma unroll
        for (int e = 0; e < 8; ++e) pk.u[e] = f2bf(W[(size_t)(f0 + e) * D_ + d]);
        *(bf16x8*)(Wt + (size_t)d * F_ + f0) = pk.v;
    }
}

// ---------------- Kernel 2: gt[b][d][m] = rs[m]*(X@W + bias)^T, bf16 (pre-scaled) ----------------
__global__ __launch_bounds__(256) void k_feat(const float* __restrict__ x,
                                              const unsigned short* __restrict__ Wt,
                                              const float* __restrict__ bias,
                                              const float* __restrict__ rs,
                                              unsigned short* __restrict__ gt) {
    __shared__ __align__(16) unsigned char sX[64 * 128 * 2];
    __shared__ __align__(16) unsigned char sW[128 * 128 * 2];
    const int t = threadIdx.x;
    const int R0 = blockIdx.x * 64;

    // stage Wt via global_load_lds: linear LDS dest + inverse-swizzled global source
#pragma unroll
    for (int j = 0; j < 8; ++j) {
        int c = j * 256 + t;
        unsigned L = (unsigned)c * 16u;
        unsigned lg = L ^ (((L >> 8) & 7u) << 4);
        const unsigned char* src = (const unsigned char*)Wt + lg;
        __builtin_amdgcn_global_load_lds(
            (const __attribute__((address_space(1))) void*)src,
            (__attribute__((address_space(3))) void*)(sW + L), 16, 0, 0);
    }
#pragma unroll
    for (int j = 0; j < 4; ++j) {
        int c = j * 256 + t;
        int row = c >> 4, sub = c & 15;
        const float4* src = (const float4*)(x + (size_t)(R0 + row) * F_ + sub * 8);
        float4 v0 = src[0], v1 = src[1];
        union { bf16x8 v; unsigned short u[8]; } pk;
        pk.u[0] = f2bf(v0.x); pk.u[1] = f2bf(v0.y); pk.u[2] = f2bf(v0.z); pk.u[3] = f2bf(v0.w);
        pk.u[4] = f2bf(v1.x); pk.u[5] = f2bf(v1.y); pk.u[6] = f2bf(v1.z); pk.u[7] = f2bf(v1.w);
        unsigned byte = (unsigned)(row * 256 + sub * 16);
        byte ^= ((byte >> 8) & 7u) << 4;
        *(bf16x8*)(sX + byte) = pk.v;
    }
    __syncthreads();

    const int w = t >> 6, l = t & 63, lr = l & 15, lh = l >> 4;
    f32x4 acc[8];
#pragma unroll
    for (int j = 0; j < 8; ++j) acc[j] = (f32x4){0.f, 0.f, 0.f, 0.f};

#pragma unroll
    for (int ks = 0; ks < 4; ++ks) {
        unsigned abyte = (unsigned)((w * 16 + lr) * 256 + lh * 16 + ks * 64);
        abyte ^= ((abyte >> 8) & 7u) << 4;
        bf16x8 a = *(const bf16x8*)(sX + abyte);
#pragma unroll
        for (int j = 0; j < 8; ++j) {
            unsigned bbyte = (unsigned)((j * 16 + lr) * 256 + lh * 16 + ks * 64);
            bbyte ^= ((bbyte >> 8) & 7u) << 4;
            bf16x8 bb = *(const bf16x8*)(sW + bbyte);
            acc[j] = __builtin_amdgcn_mfma_f32_16x16x32_bf16(a, bb, acc[j], 0, 0, 0);
        }
    }

    // epilogue: (acc + bias) * rs[m], store transposed bf16
    const int m0 = R0 + w * 16 + lh * 4;
    float4 r4 = *(const float4*)(rs + m0);
    float rr[4] = {r4.x, r4.y, r4.z, r4.w};
#pragma unroll
    for (int j = 0; j < 8; ++j) {
        int d = j * 16 + lr;
        float bv = bias[d];
#pragma unroll
        for (int r = 0; r < 4; ++r) {
            int m = m0 + r;
            int b = m >> 11, n = m & (N_ - 1);
            gt[((size_t)b * D_ + d) * N_ + n] = f2bf((acc[j][r] + bv) * rr[r]);
        }
    }
}

// ---------------- Kernel 3: out = relu(rs[n] * (adj @ gt^T)) ----------------
// 512 blocks, 512 thr. BM=32, BN=128, BK=128. 8 waves = 2 K-groups x 4 col-groups,
// each wave a 32x32 tile over half the kk-slices. Partial-sum merge via LDS at end.
__global__ __launch_bounds__(512) void k_gcn(const float* __restrict__ adj,
                                             const unsigned short* __restrict__ gt,
                                             const float* __restrict__ rs,
                                             float* __restrict__ out) {
    __shared__ __align__(16) unsigned char sA[2][32 * 128 * 2];    // adj tile bf16, 256B rows, swz
    __shared__ __align__(16) unsigned char sB[2][128 * 128 * 2];   // gt tile [d][m] bf16, swz

    unsigned bid = blockIdx.x;
    unsigned wg = (bid & 7u) * 64u + (bid >> 3);
    const int b = (int)(wg >> 6);
    const int R0 = (int)(wg & 63u) * 32;

    const float* adjB = adj + (size_t)b * N_ * N_ + (size_t)R0 * N_;
    const unsigned short* gtB = gt + (size_t)b * D_ * N_;
    const float* rsB = rs + (size_t)b * N_;

    const int t = threadIdx.x;
    const int w = t >> 6, l = t & 63, lr = l & 15, lh = l >> 4;
    const int kg = w >> 2, cg = w & 3;   // K-group, col-group; wave tile 32 rows x 32 cols

    auto stage = [&](int bufidx, int k0) {
        unsigned char* sBb = sB[bufidx];
#pragma unroll
        for (int i = 0; i < 4; ++i) {
            int c = i * 512 + t;
            unsigned L = (unsigned)c * 16u;
            unsigned lg = L ^ (((L >> 8) & 7u) << 4);
            int d = (int)(lg >> 8);
            int mloc = (int)(lg & 255u) >> 1;
            const unsigned short* g = gtB + (size_t)d * N_ + k0 + mloc;
            __builtin_amdgcn_global_load_lds(
                (const __attribute__((address_space(1))) void*)g,
                (__attribute__((address_space(3))) void*)(sBb + L), 16, 0, 0);
        }
        {
            int row = t >> 4, sub = t & 15;
            const float4* src = (const float4*)(adjB + (size_t)row * N_ + k0 + sub * 8);
            float4 v0 = src[0], v1 = src[1];
            union { bf16x8 v; unsigned short u[8]; } pk;
            pk.u[0] = f2bf(v0.x); pk.u[1] = f2bf(v0.y);
            pk.u[2] = f2bf(v0.z); pk.u[3] = f2bf(v0.w);
            pk.u[4] = f2bf(v1.x); pk.u[5] = f2bf(v1.y);
            pk.u[6] = f2bf(v1.z); pk.u[7] = f2bf(v1.w);
            unsigned byte = (unsigned)(row * 256 + sub * 16);
            byte ^= ((byte >> 8) & 7u) << 4;
            *(bf16x8*)(sA[bufidx] + byte) = pk.v;
        }
    };

    f32x4 acc[2][2];
#pragma unroll
    for (int i = 0; i < 2; ++i)
#pragma unroll
        for (int jn = 0; jn < 2; ++jn) acc[i][jn] = (f32x4){0.f, 0.f, 0.f, 0.f};

    stage(0, 0);
    __syncthreads();

    const int NITER = N_ / 128;  // 16
    for (int it = 0; it < NITER; ++it) {
        int cur = it & 1;
        if (it + 1 < NITER) stage(cur ^ 1, (it + 1) * 128);

        const unsigned char* pA = sA[cur];
        const unsigned char* pB = sB[cur];
#pragma unroll
        for (int kk2 = 0; kk2 < 2; ++kk2) {
            const int kk = kg * 2 + kk2;
            bf16x8 a[2], bb[2];
#pragma unroll
            for (int i = 0; i < 2; ++i) {
                unsigned byte = (unsigned)((i * 16 + lr) * 256 + lh * 16 + kk * 64);
                byte ^= ((byte >> 8) & 7u) << 4;
                a[i] = *(const bf16x8*)(pA + byte);
            }
#pragma unroll
            for (int jn = 0; jn < 2; ++jn) {
                int d = cg * 32 + jn * 16 + lr;
                unsigned byte = (unsigned)(d * 256 + lh * 16 + kk * 64);
                byte ^= ((byte >> 8) & 7u) << 4;
                bb[jn] = *(const bf16x8*)(pB + byte);
            }
#pragma unroll
            for (int i = 0; i < 2; ++i)
#pragma unroll
                for (int jn = 0; jn < 2; ++jn)
                    acc[i][jn] = __builtin_amdgcn_mfma_f32_16x16x32_bf16(a[i], bb[jn], acc[i][jn], 0, 0, 0);
        }
        __syncthreads();
    }

    // ---- merge the two K-groups' partials via (dead) sA, then store ----
    float* sO = (float*)sA;   // 32 x 128 f32 = 16 KB
    if (kg == 1) {
#pragma unroll
        for (int i = 0; i < 2; ++i)
#pragma unroll
            for (int jn = 0; jn < 2; ++jn)
#pragma unroll
                for (int r = 0; r < 4; ++r) {
                    int rowl = i * 16 + lh * 4 + r;
                    int d = cg * 32 + jn * 16 + lr;
                    sO[rowl * 128 + d] = acc[i][jn][r];
                }
    }
    __syncthreads();
    if (kg == 0) {
#pragma unroll
        for (int i = 0; i < 2; ++i) {
            float4 r4 = *(const float4*)(rsB + R0 + i * 16 + lh * 4);
            float rr[4] = {r4.x, r4.y, r4.z, r4.w};
#pragma unroll
            for (int r = 0; r < 4; ++r) {
                int rowl = i * 16 + lh * 4 + r;
#pragma unroll
                for (int jn = 0; jn < 2; ++jn) {
                    int d = cg * 32 + jn * 16 + lr;
                    float v = (acc[i][jn][r] + sO[rowl * 128 + d]) * rr[r];
                    out[((size_t)(b * N_ + R0 + rowl)) * D_ + d] = fmaxf(v, 0.f);
                }
            }
        }
    }
}

extern "C" void kernel_launch(void* const* d_in, const int* in_sizes, int n_in,
                              void* d_out, int out_size, void* d_ws, size_t ws_size,
                              hipStream_t stream) {
    const float* inputs = (const float*)d_in[0];   // [B,N,F]
    const float* adj    = (const float*)d_in[1];   // [B,N,N]
    const float* Wk     = (const float*)d_in[2];   // [F,D]
    const float* Wb     = (const float*)d_in[3];   // [D]
    float* out = (float*)d_out;

    float* rs = (float*)d_ws;                                            // 64 KB
    unsigned short* gt = (unsigned short*)((char*)d_ws + 65536);         // 4 MB
    unsigned short* Wt = (unsigned short*)((char*)d_ws + 65536 + (size_t)B_ * D_ * N_ * 2); // 32 KB

    k_degwt<<<4096 + 8, 256, 0, stream>>>(adj, Wk, rs, Wt);
    k_feat <<<(B_ * N_) / 64, 256, 0, stream>>>(inputs, Wt, Wb, rs, gt);
    k_gcn  <<<B_ * (N_ / 32), 512, 0, stream>>>(adj, gt, rs, out);
}

// Round 5
// 55.396 us; speedup vs baseline: 1.1434x; 1.0044x over previous
//
#include <hip/hip_runtime.h>
#include <hip/hip_bf16.h>
#include <stdint.h>

#define B_ 8
#define N_ 2048
#define F_ 128
#define D_ 128

typedef short bf16x8 __attribute__((ext_vector_type(8)));
typedef float f32x4 __attribute__((ext_vector_type(4)));

__device__ __forceinline__ unsigned short f2bf(float f) {
    unsigned u = __float_as_uint(f);
    u += 0x7fffu + ((u >> 16) & 1u);
    return (unsigned short)(u >> 16);
}

// ---------------- Kernel 1: degrees -> rsqrt  (+ W transpose in tail blocks) ----------------
__global__ __launch_bounds__(256) void k_degwt(const float* __restrict__ adj,
                                               const float* __restrict__ W,
                                               float* __restrict__ rs,
                                               unsigned short* __restrict__ Wt) {
    if (blockIdx.x < 4096) {
        const int wave = threadIdx.x >> 6, lane = threadIdx.x & 63;
        const int row = blockIdx.x * 4 + wave;          // 0..B_*N_-1
        const float4* p = (const float4*)(adj + (size_t)row * N_);
        float s = 0.f;
#pragma unroll
        for (int j = 0; j < 8; ++j) {
            float4 v = p[j * 64 + lane];
            s += (v.x + v.y) + (v.z + v.w);
        }
#pragma unroll
        for (int m = 1; m < 64; m <<= 1) s += __shfl_xor(s, m, 64);
        if (lane == 0) rs[row] = (s > 0.f) ? (1.0f / sqrtf(s)) : 0.f;
    } else {
        int c = (blockIdx.x - 4096) * 256 + threadIdx.x;
        int d = c >> 4, f0 = (c & 15) * 8;
        union { bf16x8 v; unsigned short u[8]; } pk;
#pragma unroll
        for (int e = 0; e < 8; ++e) pk.u[e] = f2bf(W[(size_t)(f0 + e) * D_ + d]);
        *(bf16x8*)(Wt + (size_t)d * F_ + f0) = pk.v;
    }
}

// ---------------- Kernel 2: gt[b][d][m] = rs[m]*(X@W + bias)^T, bf16 (pre-scaled) ----------------
__global__ __launch_bounds__(256) void k_feat(const float* __restrict__ x,
                                              const unsigned short* __restrict__ Wt,
                                              const float* __restrict__ bias,
                                              const float* __restrict__ rs,
                                              unsigned short* __restrict__ gt) {
    __shared__ __align__(16) unsigned char sX[64 * 128 * 2];
    __shared__ __align__(16) unsigned char sW[128 * 128 * 2];
    const int t = threadIdx.x;
    const int R0 = blockIdx.x * 64;

#pragma unroll
    for (int j = 0; j < 8; ++j) {
        int c = j * 256 + t;
        unsigned L = (unsigned)c * 16u;
        unsigned lg = L ^ (((L >> 8) & 7u) << 4);
        const unsigned char* src = (const unsigned char*)Wt + lg;
        __builtin_amdgcn_global_load_lds(
            (const __attribute__((address_space(1))) void*)src,
            (__attribute__((address_space(3))) void*)(sW + L), 16, 0, 0);
    }
#pragma unroll
    for (int j = 0; j < 4; ++j) {
        int c = j * 256 + t;
        int row = c >> 4, sub = c & 15;
        const float4* src = (const float4*)(x + (size_t)(R0 + row) * F_ + sub * 8);
        float4 v0 = src[0], v1 = src[1];
        union { bf16x8 v; unsigned short u[8]; } pk;
        pk.u[0] = f2bf(v0.x); pk.u[1] = f2bf(v0.y); pk.u[2] = f2bf(v0.z); pk.u[3] = f2bf(v0.w);
        pk.u[4] = f2bf(v1.x); pk.u[5] = f2bf(v1.y); pk.u[6] = f2bf(v1.z); pk.u[7] = f2bf(v1.w);
        unsigned byte = (unsigned)(row * 256 + sub * 16);
        byte ^= ((byte >> 8) & 7u) << 4;
        *(bf16x8*)(sX + byte) = pk.v;
    }
    __syncthreads();

    const int w = t >> 6, l = t & 63, lr = l & 15, lh = l >> 4;
    f32x4 acc[8];
#pragma unroll
    for (int j = 0; j < 8; ++j) acc[j] = (f32x4){0.f, 0.f, 0.f, 0.f};

#pragma unroll
    for (int ks = 0; ks < 4; ++ks) {
        unsigned abyte = (unsigned)((w * 16 + lr) * 256 + lh * 16 + ks * 64);
        abyte ^= ((abyte >> 8) & 7u) << 4;
        bf16x8 a = *(const bf16x8*)(sX + abyte);
#pragma unroll
        for (int j = 0; j < 8; ++j) {
            unsigned bbyte = (unsigned)((j * 16 + lr) * 256 + lh * 16 + ks * 64);
            bbyte ^= ((bbyte >> 8) & 7u) << 4;
            bf16x8 bb = *(const bf16x8*)(sW + bbyte);
            acc[j] = __builtin_amdgcn_mfma_f32_16x16x32_bf16(a, bb, acc[j], 0, 0, 0);
        }
    }

    const int m0 = R0 + w * 16 + lh * 4;
    float4 r4 = *(const float4*)(rs + m0);
    float rr[4] = {r4.x, r4.y, r4.z, r4.w};
#pragma unroll
    for (int j = 0; j < 8; ++j) {
        int d = j * 16 + lr;
        float bv = bias[d];
#pragma unroll
        for (int r = 0; r < 4; ++r) {
            int m = m0 + r;
            int b = m >> 11, n = m & (N_ - 1);
            gt[((size_t)b * D_ + d) * N_ + n] = f2bf((acc[j][r] + bv) * rr[r]);
        }
    }
}

// ---------------- Kernel 3: out = relu(rs[n] * (adj @ gt^T)) ----------------
// 512 blocks (2/CU), 512 thr, BM=32 BN=128 BK=128. 8 waves = 2 Kg x 4 Cg, 32x32 tiles.
// Counted-vmcnt pipeline: per stage exactly 6 VMEM (4 gload_lds B + 2 dwordx4 A->reg),
// vmcnt(6) steady-state, A write-late (T14), no vmcnt(0) drain until tail.
__global__ __launch_bounds__(512) void k_gcn(const float* __restrict__ adj,
                                             const unsigned short* __restrict__ gt,
                                             const float* __restrict__ rs,
                                             float* __restrict__ out) {
    __shared__ __align__(16) unsigned char sA[2][32 * 128 * 2];    // 2 x 8 KB
    __shared__ __align__(16) unsigned char sB[2][128 * 128 * 2];   // 2 x 32 KB  (total 80 KB)

    unsigned bid = blockIdx.x;
    unsigned wg = (bid & 7u) * 64u + (bid >> 3);
    const int b = (int)(wg >> 6);
    const int R0 = (int)(wg & 63u) * 32;

    const float* adjB = adj + (size_t)b * N_ * N_ + (size_t)R0 * N_;
    const unsigned short* gtB = gt + (size_t)b * D_ * N_;
    const float* rsB = rs + (size_t)b * N_;

    const int t = threadIdx.x;
    const int w = t >> 6, l = t & 63, lr = l & 15, lh = l >> 4;
    const int kg = w >> 2, cg = w & 3;

    // A staging geometry: thread loads 8 floats at adjB[(t>>4)*N + k0 + (t&15)*8]
    const float* aSrc = adjB + (size_t)(t >> 4) * N_ + (t & 15) * 8;
    unsigned aL = (unsigned)((t >> 4) * 256 + (t & 15) * 16);
    aL ^= ((aL >> 8) & 7u) << 4;

    // B staging geometry: 4 chunks/thread, linear LDS dest + inverse-swizzled global src
    const unsigned short* bSrc[4];
    unsigned bL[4];
#pragma unroll
    for (int i = 0; i < 4; ++i) {
        unsigned c = (unsigned)(i * 512 + t);
        unsigned L = c * 16u;
        unsigned lg = L ^ (((L >> 8) & 7u) << 4);
        bL[i] = L;
        bSrc[i] = gtB + (size_t)(lg >> 8) * N_ + ((lg & 255u) >> 1);
    }

    auto issueB = [&](int buf, int k0) {
        unsigned char* pB = sB[buf];
#pragma unroll
        for (int i = 0; i < 4; ++i) {
            __builtin_amdgcn_global_load_lds(
                (const __attribute__((address_space(1))) void*)(bSrc[i] + k0),
                (__attribute__((address_space(3))) void*)(pB + bL[i]), 16, 0, 0);
        }
    };

    f32x4 acc[2][2];
#pragma unroll
    for (int i = 0; i < 2; ++i)
#pragma unroll
        for (int jn = 0; jn < 2; ++jn) acc[i][jn] = (f32x4){0.f, 0.f, 0.f, 0.f};

    // prologue: stage(0) = 4 DMA + 2 reg loads
    issueB(0, 0);
    float4 a0 = *(const float4*)(aSrc);
    float4 a1 = *(const float4*)(aSrc + 4);

    const int NITER = N_ / 128;  // 16
    for (int it = 0; it < NITER; ++it) {
        const int cur = it & 1;
        float4 n0 = a0, n1 = a1;
        if (it + 1 < NITER) {
            issueB(cur ^ 1, (it + 1) * 128);
            const float* s = aSrc + (it + 1) * 128;
            n0 = *(const float4*)(s);
            n1 = *(const float4*)(s + 4);
            asm volatile("s_waitcnt vmcnt(6)" ::: "memory");   // stage(it) landed; it+1 in flight
        } else {
            asm volatile("s_waitcnt vmcnt(0)" ::: "memory");
        }
        __builtin_amdgcn_sched_barrier(0);

        // write-late: cvt A(it) regs -> sA[cur]
        {
            unsigned u0, u1, u2, u3;
            asm("v_cvt_pk_bf16_f32 %0, %1, %2" : "=v"(u0) : "v"(a0.x), "v"(a0.y));
            asm("v_cvt_pk_bf16_f32 %0, %1, %2" : "=v"(u1) : "v"(a0.z), "v"(a0.w));
            asm("v_cvt_pk_bf16_f32 %0, %1, %2" : "=v"(u2) : "v"(a1.x), "v"(a1.y));
            asm("v_cvt_pk_bf16_f32 %0, %1, %2" : "=v"(u3) : "v"(a1.z), "v"(a1.w));
            union { unsigned u[4]; bf16x8 v; } pk;
            pk.u[0] = u0; pk.u[1] = u1; pk.u[2] = u2; pk.u[3] = u3;
            *(bf16x8*)(sA[cur] + aL) = pk.v;
        }
        asm volatile("s_waitcnt lgkmcnt(0)" ::: "memory");
        __builtin_amdgcn_sched_barrier(0);
        __builtin_amdgcn_s_barrier();

        // compute(it)
        const unsigned char* pA = sA[cur];
        const unsigned char* pB = sB[cur];
#pragma unroll
        for (int kk2 = 0; kk2 < 2; ++kk2) {
            const int kk = kg * 2 + kk2;
            bf16x8 a[2], bb[2];
#pragma unroll
            for (int i = 0; i < 2; ++i) {
                unsigned byte = (unsigned)((i * 16 + lr) * 256 + lh * 16 + kk * 64);
                byte ^= ((byte >> 8) & 7u) << 4;
                a[i] = *(const bf16x8*)(pA + byte);
            }
#pragma unroll
            for (int jn = 0; jn < 2; ++jn) {
                int d = cg * 32 + jn * 16 + lr;
                unsigned byte = (unsigned)(d * 256 + lh * 16 + kk * 64);
                byte ^= ((byte >> 8) & 7u) << 4;
                bb[jn] = *(const bf16x8*)(pB + byte);
            }
#pragma unroll
            for (int i = 0; i < 2; ++i)
#pragma unroll
                for (int jn = 0; jn < 2; ++jn)
                    acc[i][jn] = __builtin_amdgcn_mfma_f32_16x16x32_bf16(a[i], bb[jn], acc[i][jn], 0, 0, 0);
        }
        __builtin_amdgcn_s_barrier();   // protect sB[cur] from it+1's issueB into same buf

        a0 = n0; a1 = n1;
    }

    // ---- merge the two K-groups' partials via (dead) sA, then store ----
    float* sO = (float*)sA;   // 32 x 128 f32 = 16 KB
    if (kg == 1) {
#pragma unroll
        for (int i = 0; i < 2; ++i)
#pragma unroll
            for (int jn = 0; jn < 2; ++jn)
#pragma unroll
                for (int r = 0; r < 4; ++r) {
                    int rowl = i * 16 + lh * 4 + r;
                    int d = cg * 32 + jn * 16 + lr;
                    sO[rowl * 128 + d] = acc[i][jn][r];
                }
    }
    __syncthreads();
    if (kg == 0) {
#pragma unroll
        for (int i = 0; i < 2; ++i) {
            float4 r4 = *(const float4*)(rsB + R0 + i * 16 + lh * 4);
            float rr[4] = {r4.x, r4.y, r4.z, r4.w};
#pragma unroll
            for (int r = 0; r < 4; ++r) {
                int rowl = i * 16 + lh * 4 + r;
#pragma unroll
                for (int jn = 0; jn < 2; ++jn) {
                    int d = cg * 32 + jn * 16 + lr;
                    float v = (acc[i][jn][r] + sO[rowl * 128 + d]) * rr[r];
                    out[((size_t)(b * N_ + R0 + rowl)) * D_ + d] = fmaxf(v, 0.f);
                }
            }
        }
    }
}

extern "C" void kernel_launch(void* const* d_in, const int* in_sizes, int n_in,
                              void* d_out, int out_size, void* d_ws, size_t ws_size,
                              hipStream_t stream) {
    const float* inputs = (const float*)d_in[0];   // [B,N,F]
    const float* adj    = (const float*)d_in[1];   // [B,N,N]
    const float* Wk     = (const float*)d_in[2];   // [F,D]
    const float* Wb     = (const float*)d_in[3];   // [D]
    float* out = (float*)d_out;

    float* rs = (float*)d_ws;                                            // 64 KB
    unsigned short* gt = (unsigned short*)((char*)d_ws + 65536);         // 4 MB
    unsigned short* Wt = (unsigned short*)((char*)d_ws + 65536 + (size_t)B_ * D_ * N_ * 2); // 32 KB

    k_degwt<<<4096 + 8, 256, 0, stream>>>(adj, Wk, rs, Wt);
    k_feat <<<(B_ * N_) / 64, 256, 0, stream>>>(inputs, Wk == nullptr ? nullptr : Wt, Wb, rs, gt);
    k_gcn  <<<B_ * (N_ / 32), 512, 0, stream>>>(adj, gt, rs, out);
}